// Round 1
// baseline (392.037 us; speedup 1.0000x reference)
//
#include <hip/hip_runtime.h>

// Problem constants (from reference)
#define N_  4
#define C_  64
#define H_  160
#define W_  320
#define G_  8
#define CG_ 8
#define D_  48

#define ROWS_PER_BLK 4      // h-rows per block
#define TPB (ROWS_PER_BLK * (W_ / 4))   // 4*80 = 320 threads
#define HW_ (H_ * W_)       // 51200, channel stride
// swizzled LDS row size: max index = 319 + (319>>5) = 328 -> pad to 336 (16-mult)
#define SWZW 336

// swz(w) = w + (w>>5): injective (monotone), rotates bank mapping by 1 every
// 32 w (= every 8 lanes at lane-stride-4) -> 2 lanes/bank = conflict-free.
__device__ __forceinline__ int swz_idx(int w) { return w + (w >> 5); }

__global__ __launch_bounds__(TPB) void gcv_kernel(
    const float* __restrict__ l, const float* __restrict__ r,
    float* __restrict__ out) {
  const int n   = blockIdx.z;   // 0..3
  const int g   = blockIdx.y;   // 0..7
  const int hb  = blockIdx.x;   // 0..39
  const int tid = threadIdx.x;  // 0..319
  const int row = tid / 80;     // 0..3  (h-row within block)
  const int col = tid % 80;     // 0..79
  const int w0  = col * 4;
  const int h   = hb * ROWS_PER_BLK + row;

  __shared__ float r_lds[ROWS_PER_BLK * CG_ * SWZW];  // 43,008 B

  // Input base for this (n, g, h, w0); k advances by HW_.
  const int in_base = ((n * C_ + g * CG_) * H_ + h) * W_ + w0;
  const float* lp = l + in_base;
  const float* rp = r + in_base;

  float lv[4][8];    // l values: lv[j][k] = l[8g+k][h][w0+j]
  float slot[4][8];  // sliding r window, circular over j-slots

  const int sb = w0 + (w0 >> 5);  // swizzled base; w0..w0+3 share (w>>5)
  float* myrow = &r_lds[(row * CG_) * SWZW];

  #pragma unroll
  for (int k = 0; k < 8; ++k) {
    const float4 lq = *reinterpret_cast<const float4*>(lp + k * HW_);
    lv[0][k] = lq.x; lv[1][k] = lq.y; lv[2][k] = lq.z; lv[3][k] = lq.w;
    const float4 rq = *reinterpret_cast<const float4*>(rp + k * HW_);
    // Prime d=0 window: output j uses r[w0+j] -> slot[(j-0)&3] = slot[j]
    slot[0][k] = rq.x; slot[1][k] = rq.y; slot[2][k] = rq.z; slot[3][k] = rq.w;
    float* lr = myrow + k * SWZW;
    lr[sb + 0] = rq.x; lr[sb + 1] = rq.y; lr[sb + 2] = rq.z; lr[sb + 3] = rq.w;
  }
  __syncthreads();

  // Output base: out[n][g][d][h][w]
  float* op = out + ((n * G_ + g) * D_ * H_ + h) * W_ + w0;

  for (int d4 = 0; d4 < D_; d4 += 4) {
    #pragma unroll
    for (int p = 0; p < 4; ++p) {
      const int d = d4 + p;
      // Invariant: slot[(j-d)&3][k] == r[8g+k][h][w0+j-d] (valid when idx>=0)
      float o[4];
      #pragma unroll
      for (int j = 0; j < 4; ++j) {
        float acc = 0.0f;
        #pragma unroll
        for (int k = 0; k < 8; ++k)
          acc += lv[j][k] * slot[(j - p + 4) & 3][k];
        o[j] = (w0 + j >= d) ? acc * 0.125f : 1.0f;
      }
      *reinterpret_cast<float4*>(op + d * HW_) =
          make_float4(o[0], o[1], o[2], o[3]);
      // Slide window: slot[(3-d)&3] (no longer needed) <- r[w0-d-1]
      int widx = w0 - d - 1;
      int cw = widx < 0 ? 0 : widx;    // clamp; garbage only feeds w<d lanes
      int a = cw + (cw >> 5);
      #pragma unroll
      for (int k = 0; k < 8; ++k)
        slot[(3 - p) & 3][k] = myrow[k * SWZW + a];
    }
  }
}

extern "C" void kernel_launch(void* const* d_in, const int* in_sizes, int n_in,
                              void* d_out, int out_size, void* d_ws, size_t ws_size,
                              hipStream_t stream) {
  const float* l = (const float*)d_in[0];
  const float* r = (const float*)d_in[1];
  float* out = (float*)d_out;
  dim3 grid(H_ / ROWS_PER_BLK, G_, N_);  // 40 x 8 x 4 = 1280 blocks
  dim3 block(TPB);                        // 320 threads = 5 waves
  hipLaunchKernelGGL(gcv_kernel, grid, block, 0, stream, l, r, out);
}

// Round 2
// 380.569 us; speedup vs baseline: 1.0301x; 1.0301x over previous
//
#include <hip/hip_runtime.h>

// Problem constants (from reference)
#define N_  4
#define C_  64
#define H_  160
#define W_  320
#define G_  8
#define CG_ 8
#define D_  48

#define ROWS_PER_BLK 4                   // h-rows per block
#define TPB (ROWS_PER_BLK * (W_ / 4))    // 4*80 = 320 threads = 5 waves
#define HW_ (H_ * W_)                    // 51200, channel stride

// LDS: r rows for this block, layout [row][k][w], w contiguous (320 floats).
// 4*8*320*4 B = 40,960 B -> up to 4 blocks/CU by LDS.
// All LDS access is ds_read_b128/ds_write_b128 with lane-contiguous addresses
// -> conflict-free without swizzle.

__global__ __launch_bounds__(TPB) void gcv_kernel(
    const float* __restrict__ l, const float* __restrict__ r,
    float* __restrict__ out) {
  const int n   = blockIdx.z;   // 0..3
  const int g   = blockIdx.y;   // 0..7
  const int hb  = blockIdx.x;   // 0..39
  const int tid = threadIdx.x;  // 0..319
  const int row = tid / 80;     // 0..3
  const int col = tid % 80;     // 0..79
  const int w0  = col * 4;
  const int h   = hb * ROWS_PER_BLK + row;

  __shared__ float r_lds[ROWS_PER_BLK * CG_ * W_];

  const int in_base = ((n * C_ + g * CG_) * H_ + h) * W_ + w0;
  const float* lp = l + in_base;
  const float* rp = r + in_base;

  float lv[4][8];          // lv[j][k] = l[8g+k][h][w0+j]
  float X[8][4], Y[8][4];  // ping-pong window halves, [k][i] over 4 columns

  float* myrow = &r_lds[row * CG_ * W_];

  // Stage: l -> regs, r -> regs (initial high half) + LDS.
  #pragma unroll
  for (int k = 0; k < 8; ++k) {
    const float4 lq = *reinterpret_cast<const float4*>(lp + k * HW_);
    lv[0][k] = lq.x; lv[1][k] = lq.y; lv[2][k] = lq.z; lv[3][k] = lq.w;
    const float4 rq = *reinterpret_cast<const float4*>(rp + k * HW_);
    // Window for d4=0 covers cols [w0-4, w0+4); high half (cols w0..w0+3) = rq.
    X[k][0] = rq.x; X[k][1] = rq.y; X[k][2] = rq.z; X[k][3] = rq.w;
    *reinterpret_cast<float4*>(&myrow[k * W_ + w0]) = rq;
  }
  __syncthreads();

  // Low half for d4=0: cols [w0-4, w0-1], clamped (garbage only feeds w<d).
  {
    int cb = w0 - 4; if (cb < 0) cb = 0;
    #pragma unroll
    for (int k = 0; k < 8; ++k) {
      const float4 v = *reinterpret_cast<const float4*>(&myrow[k * W_ + cb]);
      Y[k][0] = v.x; Y[k][1] = v.y; Y[k][2] = v.z; Y[k][3] = v.w;
    }
  }

  float* op = out + ((n * G_ + g) * D_ * H_ + h) * W_ + w0;

  // Invariant at iter t (d4 = 4t): window cols c..c+7, c = w0 - d4 - 4.
  //   L[k][i] = r[k][c+i]  (i=0..3),  H[k][i] = r[k][c+4+i].
  // Output (d=d4+p, j) reads window offset 4+j-p in [1,7].
  #pragma unroll
  for (int t = 0; t < D_ / 4; ++t) {
    const int d4 = 4 * t;
    float (&H)[8][4] = (t & 1) ? Y : X;  // compile-time after unroll
    float (&L)[8][4] = (t & 1) ? X : Y;

    #pragma unroll
    for (int p = 0; p < 4; ++p) {
      const int d = d4 + p;
      float o[4];
      #pragma unroll
      for (int j = 0; j < 4; ++j) {
        const int off = 4 + j - p;  // 1..7, compile-time
        float acc = 0.0f;
        #pragma unroll
        for (int k = 0; k < 8; ++k) {
          const float rv = (off >= 4) ? H[k][off - 4] : L[k][off];
          acc += lv[j][k] * rv;
        }
        o[j] = (w0 + j >= d) ? acc * 0.125f : 1.0f;
      }
      *reinterpret_cast<float4*>(op + d * HW_) =
          make_float4(o[0], o[1], o[2], o[3]);
    }

    // Prefetch next iteration's low half into H's bank (dead after p=3).
    // Next window base: w0 - (d4+4) - 4. Clamp keeps 16B alignment; when it
    // triggers, all 4 true columns are negative -> only masked outputs read it.
    if (t < D_ / 4 - 1) {
      int cb = w0 - d4 - 8; if (cb < 0) cb = 0;
      #pragma unroll
      for (int k = 0; k < 8; ++k) {
        const float4 v = *reinterpret_cast<const float4*>(&myrow[k * W_ + cb]);
        H[k][0] = v.x; H[k][1] = v.y; H[k][2] = v.z; H[k][3] = v.w;
      }
    }
  }
}

extern "C" void kernel_launch(void* const* d_in, const int* in_sizes, int n_in,
                              void* d_out, int out_size, void* d_ws, size_t ws_size,
                              hipStream_t stream) {
  const float* l = (const float*)d_in[0];
  const float* r = (const float*)d_in[1];
  float* out = (float*)d_out;
  dim3 grid(H_ / ROWS_PER_BLK, G_, N_);  // 40 x 8 x 4 = 1280 blocks
  dim3 block(TPB);
  hipLaunchKernelGGL(gcv_kernel, grid, block, 0, stream, l, r, out);
}